// Round 6
// baseline (388.900 us; speedup 1.0000x reference)
//
#include <hip/hip_runtime.h>
#include <math.h>

// Problem constants (from reference setup_inputs)
#define B_IMG   8
#define A_ANCH  100000
#define M_ANN   32
#define C_CLS   80
#define NTHREADS 256
#define NWAVES  (NTHREADS/64)
#define V_PER_ANCH (C_CLS/4)                    // 20 float4 per anchor row
#define AF4     (A_ANCH * V_PER_ANCH)           // 2,000,000 float4 per image
#define NBLK_A  ((A_ANCH + NTHREADS - 1) / NTHREADS)  // 391 assign blocks/image
#define NBLK_S  1024                            // stream blocks per image

// ws float layout (all slots written unconditionally -> no zero-init):
#define CLSPART_OFF 0        // [B_IMG][NBLK_S]  cls partials (stream kernel)
#define REGPART_OFF 8192     // [B_IMG][512]     reg partials (assign kernel, 391 used)
#define POSPART_OFF 12288    // [B_IMG][512]     pos partials (assign kernel)
#define CODES_OFF   16384    // int32 [B_IMG][A_ANCH] per-anchor codes

// branch-free per-float4 focal term; mask handles ignore band (code==-1)
__device__ __forceinline__ float focal4(float4 p4, int code, int c0) {
    const float m = (code != -1) ? 1.0f : 0.0f;
    float acc = 0.0f;
    const float pv[4] = {p4.x, p4.y, p4.z, p4.w};
    #pragma unroll
    for (int j = 0; j < 4; ++j) {
        const float p = fminf(fmaxf(pv[j], 1e-4f), 1.0f - 1e-4f);
        const bool t1 = (code == c0 + j);
        const float q = t1 ? (1.0f - p) : p;          // (1-p) if target==1 else p
        const float w = t1 ? 0.25f : 0.75f;           // alpha factor
        // bce both cases collapse to -log(1-q)
        acc = fmaf(m * w * q * q, -__logf(1.0f - q), acc);
    }
    return acc;
}

// ---------------------------------------------------------------------------
// Kernel A: per-anchor assignment (IoU argmax -> code) + regression loss.
// Traffic: anchors 1.6MB x8 + regr 12.8MB + codes 3.2MB write  -> ~5 us.
// ---------------------------------------------------------------------------
__global__ __launch_bounds__(NTHREADS)
void focal_assign(const float* __restrict__ regr,     // [B,A,4]
                  const float* __restrict__ anchors,  // [1,A,4]
                  const float* __restrict__ ann,      // [B,M,6]
                  float* __restrict__ ws)
{
    __shared__ float s_ann[M_ANN][6];
    __shared__ float s_area[M_ANN];
    __shared__ float s_red[2][NWAVES];

    const int b  = blockIdx.y;
    const int a0 = blockIdx.x * NTHREADS;
    const int t  = threadIdx.x;
    int* __restrict__ codes = (int*)(ws + CODES_OFF);

    if (t < M_ANN * 6) ((float*)s_ann)[t] = ann[(size_t)b * M_ANN * 6 + t];
    __syncthreads();
    if (t < M_ANN)
        s_area[t] = (s_ann[t][2] - s_ann[t][0]) * (s_ann[t][3] - s_ann[t][1]);
    __syncthreads();

    float reg_acc = 0.0f;
    float pos_cnt = 0.0f;

    const int a = a0 + t;
    if (a < A_ANCH) {
        const float4 ab = ((const float4*)anchors)[a];
        const float aw = ab.z - ab.x;
        const float ah = ab.w - ab.y;
        const float acx = ab.x + 0.5f * aw;
        const float acy = ab.y + 0.5f * ah;
        const float area_a = aw * ah;

        float best = -2.0f;
        int   bm   = 0;
        #pragma unroll 8
        for (int m = 0; m < M_ANN; ++m) {
            float iou;
            if (s_ann[m][4] == -1.0f) {
                iou = -1.0f;                       // padding mask
            } else {
                float iw = fminf(ab.z, s_ann[m][2]) - fmaxf(ab.x, s_ann[m][0]);
                float ih = fminf(ab.w, s_ann[m][3]) - fmaxf(ab.y, s_ann[m][1]);
                float inter = fmaxf(iw, 0.0f) * fmaxf(ih, 0.0f);
                float ua = fmaxf(area_a + s_area[m] - inter, 1e-8f);
                iou = inter / ua;
            }
            if (iou > best) { best = iou; bm = m; } // strict '>' = first max (JAX argmax)
        }

        const bool pos = (best >= 0.5f);
        int code;
        if (pos)                 code = (int)s_ann[bm][4];
        else if (best < 0.4f)    code = -2;
        else                     code = -1;
        codes[(size_t)b * A_ANCH + a] = code;       // coalesced int store

        if (pos) {
            pos_cnt = 1.0f;
            const float gx1 = s_ann[bm][0], gy1 = s_ann[bm][1];
            const float gx2 = s_ann[bm][2], gy2 = s_ann[bm][3];
            float gw = gx2 - gx1, gh = gy2 - gy1;
            const float gcx = gx1 + 0.5f * gw;
            const float gcy = gy1 + 0.5f * gh;
            gw = fmaxf(gw, 1.0f); gh = fmaxf(gh, 1.0f);
            const float t0 = (gcx - acx) / aw * 10.0f;   // /0.1
            const float t1v = (gcy - acy) / ah * 10.0f;
            const float t2 = logf(gw / aw) * 5.0f;       // /0.2
            const float t3 = logf(gh / ah) * 5.0f;

            const float4 rg = ((const float4*)regr)[(size_t)b * A_ANCH + a];
            const float d0 = fabsf(t0  - rg.x);
            const float d1 = fabsf(t1v - rg.y);
            const float d2 = fabsf(t2  - rg.z);
            const float d3 = fabsf(t3  - rg.w);
            const float th = 1.0f / 9.0f;
            const float c_ = 0.5f / 9.0f;
            reg_acc += (d0 <= th) ? 4.5f * d0 * d0 : d0 - c_;
            reg_acc += (d1 <= th) ? 4.5f * d1 * d1 : d1 - c_;
            reg_acc += (d2 <= th) ? 4.5f * d2 * d2 : d2 - c_;
            reg_acc += (d3 <= th) ? 4.5f * d3 * d3 : d3 - c_;
        }
    }

    #pragma unroll
    for (int off = 32; off > 0; off >>= 1) {
        reg_acc += __shfl_down(reg_acc, off, 64);
        pos_cnt += __shfl_down(pos_cnt, off, 64);
    }
    const int wave = t >> 6, lane = t & 63;
    if (lane == 0) { s_red[0][wave] = reg_acc; s_red[1][wave] = pos_cnt; }
    __syncthreads();
    if (t == 0) {
        float r = 0.f, p = 0.f;
        #pragma unroll
        for (int w = 0; w < NWAVES; ++w) { r += s_red[0][w]; p += s_red[1][w]; }
        ws[REGPART_OFF + b * 512 + blockIdx.x] = r;
        ws[POSPART_OFF + b * 512 + blockIdx.x] = p;
    }
}

// ---------------------------------------------------------------------------
// Kernel B: pure streaming focal sweep — structurally identical to the rocclr
// copy kernel (grid-stride float4, no LDS in hot loop, no barriers, low VGPR,
// 8 waves/EU). Codes read via L1-cached global loads (1/20th traffic).
// ---------------------------------------------------------------------------
__global__ __launch_bounds__(NTHREADS, 8)
void focal_stream(const float* __restrict__ cls,   // [B,A,C]
                  float* __restrict__ ws)
{
    const int b = blockIdx.y;
    const int t = threadIdx.x;
    const float4* __restrict__ cbase = (const float4*)cls + (size_t)b * AF4;
    const int*    __restrict__ cb    = (const int*)(ws + CODES_OFF) + (size_t)b * A_ANCH;

    float acc = 0.0f;
    for (int v = blockIdx.x * NTHREADS + t; v < AF4; v += NBLK_S * NTHREADS) {
        const int al = v / V_PER_ANCH;           // magic-mul division by 20
        const int c0 = (v - al * V_PER_ANCH) * 4;
        const int code = cb[al];                 // L1 line-broadcast across lanes
        acc += focal4(cbase[v], code, c0);
    }

    #pragma unroll
    for (int off = 32; off > 0; off >>= 1)
        acc += __shfl_down(acc, off, 64);
    __shared__ float s_red[NWAVES];
    const int wave = t >> 6, lane = t & 63;
    if (lane == 0) s_red[wave] = acc;
    __syncthreads();
    if (t == 0) {
        float c = 0.f;
        #pragma unroll
        for (int w = 0; w < NWAVES; ++w) c += s_red[w];
        ws[CLSPART_OFF + b * NBLK_S + blockIdx.x] = c;   // unique slot, no atomics
    }
}

// ---------------------------------------------------------------------------
// Kernel C: reduce partials and finalize both outputs.
// ---------------------------------------------------------------------------
__global__ __launch_bounds__(256)
void focal_reduce(const float* __restrict__ ws, float* __restrict__ out) {
    const int t = threadIdx.x;
    const int b = t >> 5;          // image 0..7 (group of 32 threads)
    const int j = t & 31;
    float c = 0.f, r = 0.f, p = 0.f;
    for (int i = j; i < NBLK_S; i += 32)
        c += ws[CLSPART_OFF + b * NBLK_S + i];
    for (int i = j; i < NBLK_A; i += 32) {
        r += ws[REGPART_OFF + b * 512 + i];
        p += ws[POSPART_OFF + b * 512 + i];
    }
    #pragma unroll
    for (int off = 16; off > 0; off >>= 1) {
        c += __shfl_down(c, off, 32);
        r += __shfl_down(r, off, 32);
        p += __shfl_down(p, off, 32);
    }
    __shared__ float s[B_IMG][3];
    if (j == 0) { s[b][0] = c; s[b][1] = r; s[b][2] = p; }
    __syncthreads();
    if (t == 0) {
        float cl = 0.f, rl = 0.f;
        #pragma unroll
        for (int bb = 0; bb < B_IMG; ++bb) {
            const float np  = s[bb][2];
            const float mnp = fmaxf(np, 1.0f);
            cl += s[bb][0] / mnp;
            rl += (np > 0.0f) ? s[bb][1] / (4.0f * mnp) : 0.0f;
        }
        out[0] = cl / (float)B_IMG;
        out[1] = rl / (float)B_IMG;
    }
}

extern "C" void kernel_launch(void* const* d_in, const int* in_sizes, int n_in,
                              void* d_out, int out_size, void* d_ws, size_t ws_size,
                              hipStream_t stream) {
    const float* cls     = (const float*)d_in[0];  // [B,A,C]
    const float* regr    = (const float*)d_in[1];  // [B,A,4]
    const float* anchors = (const float*)d_in[2];  // [1,A,4]
    const float* ann     = (const float*)d_in[3];  // [B,M,6]
    float* out = (float*)d_out;
    float* ws  = (float*)d_ws;

    dim3 gA(NBLK_A, B_IMG);
    focal_assign<<<gA, NTHREADS, 0, stream>>>(regr, anchors, ann, ws);

    dim3 gS(NBLK_S, B_IMG);
    focal_stream<<<gS, NTHREADS, 0, stream>>>(cls, ws);

    focal_reduce<<<1, 256, 0, stream>>>(ws, out);
}